// Round 2
// baseline (274.910 us; speedup 1.0000x reference)
//
#include <hip/hip_runtime.h>

typedef __attribute__((ext_vector_type(8))) _Float16 f16x8;
typedef __attribute__((ext_vector_type(4))) _Float16 f16x4;
typedef __attribute__((ext_vector_type(4))) float f32x4;
typedef __attribute__((ext_vector_type(2))) float f32x2;

#define MFMA16(A, Bv, Cv) __builtin_amdgcn_mfma_f32_16x16x32_f16(A, Bv, Cv, 0, 0, 0)

#define NB 8
#define CIN 512
#define NC 256
#define NQ 19
#define KP 40  // padded k-stride (halfwords) of LDS B tiles: 80B rows -> 16B-aligned b128 frags

// workspace byte offsets
#define WS_WH 0            // 131072 halfs (w_hi, fragment-linear, scaled x32)
#define WS_WL 262144       // 131072 halfs (w_lo)
#define WS_W2T 524288      // 256x256 f32 (w2 transposed)
#define WS_BIAS 786432     // 256 f32
#define WS_M 787456        // 8*19*256 f32
// total ~943 KB

// ---------------- K0: prep (fold BN scale into w, x32 scale, split fp16, w2^T, bias) ------
__global__ __launch_bounds__(256) void k_prep(
    const float* __restrict__ w1, const float* __restrict__ gamma,
    const float* __restrict__ beta, const float* __restrict__ mean,
    const float* __restrict__ var, const float* __restrict__ w2,
    char* __restrict__ ws) {
  _Float16* wh = (_Float16*)(ws + WS_WH);
  _Float16* wl = (_Float16*)(ws + WS_WL);
  float* w2t = (float*)(ws + WS_W2T);
  float* bias = (float*)(ws + WS_BIAS);
  const int bid = blockIdx.x, t = threadIdx.x;
  if (bid < 128) {
    // fragment-linear: elem e = aidx*8 + j, aidx = (kk*16 + mfq)*64 + l
    // lane l holds A[c = mfq*16 + (l&15)][k = kk*32 + (l>>4)*8 + j]
    for (int u = 0; u < 4; ++u) {
      int e = bid * 1024 + u * 256 + t;
      int j = e & 7, l6 = (e >> 3) & 63, mfq = (e >> 9) & 15, kk = e >> 13;
      int c = mfq * 16 + (l6 & 15);
      int k = kk * 32 + (l6 >> 4) * 8 + j;
      float sc = gamma[c] / sqrtf(var[c] + 1e-5f);
      float wf = w1[c * 512 + k] * sc * 32.0f;   // x32 keeps lo-part f16-normal
      _Float16 h = (_Float16)wf;
      wh[e] = h;
      wl[e] = (_Float16)(wf - (float)h);
    }
  } else if (bid < 192) {
    for (int u = 0; u < 4; ++u) {
      int e = (bid - 128) * 1024 + u * 256 + t;
      int i = e >> 8, o = e & 255;
      w2t[e] = w2[o * 256 + i];
    }
  } else {
    float sc = gamma[t] / sqrtf(var[t] + 1e-5f);
    bias[t] = beta[t] - mean[t] * sc;
  }
}

// ---------------- K1: conv1 (split-fp16 MFMA) + BN + ReLU + fused energy partials --------
// grid 2048 = 8 b * 256 s-blocks of 64; 256 threads = 4 waves (wave m-tiles of 64 channels)
__global__ __launch_bounds__(256) void k_conv1_energy(
    const float* __restrict__ x, const float* __restrict__ qx,
    const char* __restrict__ ws, float* __restrict__ part) {
  __shared__ __align__(16) char smem[22784];
  _Float16* Bh = (_Float16*)smem;               // [64][KP] halfs (5120 B)
  _Float16* Bl = (_Float16*)(smem + 5120);      // [64][KP] halfs
  float* kvq = (float*)smem;                    // [64][66] f32 epilogue overlay (16896 B)
  float* qlds = (float*)(smem + 16896);         // [19][64]
  float* blds = (float*)(smem + 21760);         // [256]

  const int tid = threadIdx.x;
  const int l = tid & 63;
  const int wm = tid >> 6;                      // wave id = channel quarter 0..3
  const int g = l >> 4, a = l & 15;
  const int bid = blockIdx.x;
  const int sblk = bid & 255;
  const int b = bid >> 8;
  const int s0 = sblk << 6;

  const f16x8* __restrict__ whv = (const f16x8*)(ws + WS_WH);
  const f16x8* __restrict__ wlv = (const f16x8*)(ws + WS_WL);
  const float* __restrict__ biasg = (const float*)(ws + WS_BIAS);

  // stage q tile + bias (regions disjoint from B tiles)
  for (int idx = tid; idx < NQ * 64; idx += 256) {
    int n = idx >> 6, s = idx & 63;
    qlds[idx] = qx[((size_t)(b * NQ + n) << 14) + s0 + s];
  }
  blds[tid] = biasg[tid];

  // B staging: thread -> 4 k-rows (kq*4..+3), 2 sigmas (sL, sL+1)
  const int sL = (tid & 31) * 2;                // local sigma 0..62
  const int kq = tid >> 5;                      // 0..7 -> k rows kq*4..kq*4+3
  const float* __restrict__ xb =
      x + (((size_t)(b * CIN + kq * 4)) << 14) + s0 + sL;

  f32x4 acc[4][4];
  const f32x4 zz = {0.f, 0.f, 0.f, 0.f};
  #pragma unroll
  for (int i = 0; i < 4; ++i)
    #pragma unroll
    for (int j = 0; j < 4; ++j) acc[i][j] = zz;

  float2 c0 = *(const float2*)(xb);
  float2 c1 = *(const float2*)(xb + (1 << 14));
  float2 c2 = *(const float2*)(xb + (2 << 14));
  float2 c3 = *(const float2*)(xb + (3 << 14));

  #pragma unroll 1
  for (int kk = 0; kk < 16; ++kk) {
    // A fragments for this k-step (L2-resident, issue early)
    f16x8 ah[4], al[4];
    #pragma unroll
    for (int mf = 0; mf < 4; ++mf) {
      int aidx = (kk * 16 + wm * 4 + mf) * 64 + l;
      ah[mf] = whv[aidx];
      al[mf] = wlv[aidx];
    }
    // convert current tile (x32 scale keeps lo normal) and write LDS
    {
      float v0[4] = {c0.x * 32.f, c1.x * 32.f, c2.x * 32.f, c3.x * 32.f};
      float v1[4] = {c0.y * 32.f, c1.y * 32.f, c2.y * 32.f, c3.y * 32.f};
      f16x4 h0, l0, h1, l1;
      #pragma unroll
      for (int q = 0; q < 4; ++q) {
        _Float16 h = (_Float16)v0[q];
        h0[q] = h; l0[q] = (_Float16)(v0[q] - (float)h);
        _Float16 h2 = (_Float16)v1[q];
        h1[q] = h2; l1[q] = (_Float16)(v1[q] - (float)h2);
      }
      *(f16x4*)&Bh[sL * KP + kq * 4] = h0;
      *(f16x4*)&Bl[sL * KP + kq * 4] = l0;
      *(f16x4*)&Bh[(sL + 1) * KP + kq * 4] = h1;
      *(f16x4*)&Bl[(sL + 1) * KP + kq * 4] = l1;
    }
    // prefetch next k-step while MFMAs run
    if (kk < 15) {
      const float* xp = xb + ((size_t)(kk + 1) << 19);
      c0 = *(const float2*)(xp);
      c1 = *(const float2*)(xp + (1 << 14));
      c2 = *(const float2*)(xp + (2 << 14));
      c3 = *(const float2*)(xp + (3 << 14));
    }
    __syncthreads();  // B tile visible
    #pragma unroll
    for (int nf = 0; nf < 4; ++nf) {
      const int sB = nf * 16 + a;
      f16x8 bh = *(const f16x8*)&Bh[sB * KP + 8 * g];
      f16x8 bl = *(const f16x8*)&Bl[sB * KP + 8 * g];
      #pragma unroll
      for (int mf = 0; mf < 4; ++mf) {
        acc[mf][nf] = MFMA16(ah[mf], bh, acc[mf][nf]);
        acc[mf][nf] = MFMA16(al[mf], bh, acc[mf][nf]);
        acc[mf][nf] = MFMA16(ah[mf], bl, acc[mf][nf]);
      }
    }
    __syncthreads();  // reads done before next overwrite
  }

  // undo x32*x32 scaling, add BN bias, ReLU
  #pragma unroll
  for (int mf = 0; mf < 4; ++mf)
    #pragma unroll
    for (int r = 0; r < 4; ++r) {
      float bi = blds[wm * 64 + mf * 16 + g * 4 + r];
      #pragma unroll
      for (int nf = 0; nf < 4; ++nf)
        acc[mf][nf][r] = fmaxf(acc[mf][nf][r] * (1.0f / 1024.0f) + bi, 0.f);
    }

  // fused energy partials: e[n][c] = sum_sigma q[n][s]*feat[c][s], 4 channel-quarter phases
  const int cl = tid & 63;
  const int tg = tid >> 6;
  const size_t pbase = (size_t)(b * 256 + sblk) * (NQ * 256);
  #pragma unroll 1
  for (int ph = 0; ph < 4; ++ph) {
    __syncthreads();
    if (wm == ph) {
      #pragma unroll
      for (int mf = 0; mf < 4; ++mf)
        #pragma unroll
        for (int nf = 0; nf < 4; ++nf)
          #pragma unroll
          for (int r = 0; r < 4; ++r)
            kvq[(mf * 16 + g * 4 + r) * 66 + nf * 16 + a] = acc[mf][nf][r];
    }
    __syncthreads();
    float a0 = 0.f, a1 = 0.f, a2 = 0.f, a3 = 0.f, a4 = 0.f;
    #pragma unroll 4
    for (int sv = 0; sv < 64; ++sv) {
      float kvv = kvq[cl * 66 + sv];
      a0 = fmaf(kvv, qlds[(tg) * 64 + sv], a0);
      a1 = fmaf(kvv, qlds[(tg + 4) * 64 + sv], a1);
      a2 = fmaf(kvv, qlds[(tg + 8) * 64 + sv], a2);
      a3 = fmaf(kvv, qlds[(tg + 12) * 64 + sv], a3);
      if (tg < 3) a4 = fmaf(kvv, qlds[(tg + 16) * 64 + sv], a4);
    }
    float* pp = part + pbase + (size_t)ph * 64 + cl;
    pp[(size_t)(tg) * 256] = a0;
    pp[(size_t)(tg + 4) * 256] = a1;
    pp[(size_t)(tg + 8) * 256] = a2;
    pp[(size_t)(tg + 12) * 256] = a3;
    if (tg < 3) pp[(size_t)(tg + 16) * 256] = a4;
  }
}

// ---------------- K2: reduce partials + softmax over c + M = attn @ w2^T ------------------
__global__ __launch_bounds__(256) void k_softmax_m(
    const float* __restrict__ part, const char* __restrict__ ws,
    float* __restrict__ Mout) {
  const int bn = blockIdx.x;
  const int b = bn / 19, n = bn % 19;
  const int t = threadIdx.x;
  const float* __restrict__ w2t = (const float*)(ws + WS_W2T);
  float e = 0.f;
  const float* pp = part + ((size_t)b * 256 * 19 + n) * 256 + t;
  for (int sb = 0; sb < 256; ++sb)
    e += pp[(size_t)sb * (19 * 256)];
  __shared__ float sred[4];
  __shared__ float attn_lds[256];
  float m = e;
  #pragma unroll
  for (int d = 1; d < 64; d <<= 1) m = fmaxf(m, __shfl_xor(m, d, 64));
  if ((t & 63) == 0) sred[t >> 6] = m;
  __syncthreads();
  m = fmaxf(fmaxf(sred[0], sred[1]), fmaxf(sred[2], sred[3]));
  float p = __expf(e - m);
  float s = p;
  #pragma unroll
  for (int d = 1; d < 64; d <<= 1) s += __shfl_xor(s, d, 64);
  __syncthreads();
  if ((t & 63) == 0) sred[t >> 6] = s;
  __syncthreads();
  s = sred[0] + sred[1] + sred[2] + sred[3];
  attn_lds[t] = p / s;
  __syncthreads();
  float macc = 0.f;
  #pragma unroll 8
  for (int i = 0; i < 256; ++i)
    macc = fmaf(attn_lds[i], w2t[i * 256 + t], macc);
  Mout[(size_t)bn * 256 + t] = macc;
}

// ---------------- K3: out[b,o,s] = sum_n M[b,n,o]*q[b,n,s] + b2[o] ------------------------
// grid 512 = 8 b * 64 s-chunks of 256; 256 threads
__global__ __launch_bounds__(256, 2) void k_out(
    const float* __restrict__ qx, const float* __restrict__ Mg,
    const float* __restrict__ b2, float* __restrict__ out) {
  const int bid = blockIdx.x;
  const int b = bid >> 6, sc = bid & 63;
  const int s0 = sc * 256;
  const int t = threadIdx.x;
  __shared__ float qlds[19 * 256];
  for (int idx = t; idx < 19 * 256; idx += 256) {
    int n = idx >> 8, s = idx & 255;
    qlds[idx] = qx[((size_t)(b * NQ + n) << 14) + s0 + s];
  }
  __syncthreads();
  const int tg = t >> 4, a2 = (t & 15) * 2;
  #pragma unroll 1
  for (int ocg = 0; ocg < 4; ++ocg) {
    float m[4][19];
    float bi[4];
    #pragma unroll
    for (int oj = 0; oj < 4; ++oj) {
      int o = (ocg * 4 + oj) * 16 + tg;
      bi[oj] = b2[o];
      #pragma unroll
      for (int n = 0; n < 19; ++n)
        m[oj][n] = Mg[((size_t)b * NQ + n) * 256 + o];
    }
    #pragma unroll 1
    for (int sp = 0; sp < 8; ++sp) {
      int s = sp * 32 + a2;
      f32x2 acc2[4];
      #pragma unroll
      for (int oj = 0; oj < 4; ++oj) { acc2[oj].x = bi[oj]; acc2[oj].y = bi[oj]; }
      #pragma unroll
      for (int n = 0; n < 19; ++n) {
        f32x2 q2 = *(const f32x2*)&qlds[n * 256 + s];
        #pragma unroll
        for (int oj = 0; oj < 4; ++oj) {
          acc2[oj].x = fmaf(m[oj][n], q2.x, acc2[oj].x);
          acc2[oj].y = fmaf(m[oj][n], q2.y, acc2[oj].y);
        }
      }
      #pragma unroll
      for (int oj = 0; oj < 4; ++oj) {
        int o = (ocg * 4 + oj) * 16 + tg;
        *(f32x2*)&out[((size_t)(b * NC + o) << 14) + s0 + s] = acc2[oj];
      }
    }
  }
}

extern "C" void kernel_launch(void* const* d_in, const int* in_sizes, int n_in,
                              void* d_out, int out_size, void* d_ws, size_t ws_size,
                              hipStream_t stream) {
  const float* x     = (const float*)d_in[0];
  const float* cx    = (const float*)d_in[1];
  const float* w1    = (const float*)d_in[2];
  const float* gamma = (const float*)d_in[3];
  const float* beta  = (const float*)d_in[4];
  const float* mean  = (const float*)d_in[5];
  const float* var   = (const float*)d_in[6];
  const float* w2    = (const float*)d_in[7];
  const float* b2    = (const float*)d_in[8];
  char* ws = (char*)d_ws;
  float* out = (float*)d_out;
  // energy partials [8][256][19][256] f32 (~40 MB) overlay d_out; consumed by k_softmax_m
  // before k_out overwrites the full output. Deterministic: fully rewritten every launch.
  float* part = (float*)d_out;
  float* Mptr = (float*)(ws + WS_M);

  k_prep<<<193, 256, 0, stream>>>(w1, gamma, beta, mean, var, w2, ws);
  k_conv1_energy<<<2048, 256, 0, stream>>>(x, cx, ws, part);
  k_softmax_m<<<152, 256, 0, stream>>>(part, ws, Mptr);
  k_out<<<512, 256, 0, stream>>>(cx, Mptr, b2, out);
}